// Round 1
// baseline (28999.387 us; speedup 1.0000x reference)
//
#include <hip/hip_runtime.h>

#define NP 50000
#define NL 10000
#define PLEN 5
#define NE (NP * PLEN)
#define DD 32
#define NG 96   /* 3*32 */
#define RUU 256
#define TITERS 8

__device__ __forceinline__ float sigmoidf_(float a) {
    return 1.0f / (1.0f + __expf(-a));
}
__device__ __forceinline__ float tanhf_(float a) {
    a = fminf(fmaxf(a, -15.0f), 15.0f);
    float t = __expf(2.0f * a);
    return (t - 1.0f) / (t + 1.0f);
}

// One GRU step (torch gate math). Weights/biases live in LDS (uniform
// addresses -> broadcast reads, bank-conflict-free). x,h are register arrays.
__device__ __forceinline__ void gru_step(const float* __restrict__ sWi,
                                         const float* __restrict__ sWh,
                                         const float* __restrict__ sbi,
                                         const float* __restrict__ sbh,
                                         const float* __restrict__ x,
                                         float* __restrict__ h) {
    float hnew[DD];
#pragma unroll
    for (int j = 0; j < DD; j++) {
        float ir  = sbi[j];
        float iz  = sbi[j + 32];
        float inn = sbi[j + 64];
        float hr  = sbh[j];
        float hz  = sbh[j + 32];
        float hnn = sbh[j + 64];
#pragma unroll
        for (int k = 0; k < DD; k++) {
            ir  = fmaf(x[k], sWi[j * DD + k], ir);
            iz  = fmaf(x[k], sWi[(j + 32) * DD + k], iz);
            inn = fmaf(x[k], sWi[(j + 64) * DD + k], inn);
            hr  = fmaf(h[k], sWh[j * DD + k], hr);
            hz  = fmaf(h[k], sWh[(j + 32) * DD + k], hz);
            hnn = fmaf(h[k], sWh[(j + 64) * DD + k], hnn);
        }
        float r = sigmoidf_(ir + hr);
        float z = sigmoidf_(iz + hz);
        float n = tanhf_(inn + r * hnn);
        hnew[j] = (1.0f - z) * n + z * h[j];
    }
#pragma unroll
    for (int j = 0; j < DD; j++) h[j] = hnew[j];
}

__global__ __launch_bounds__(256) void k_init(
    const float* __restrict__ traffic, const float* __restrict__ packets,
    const float* __restrict__ tdp, const float* __restrict__ capacity,
    float* __restrict__ path_state, float* __restrict__ link_state,
    int* __restrict__ lens) {
    int i = blockIdx.x * 256 + threadIdx.x;
    if (i < NP) {
        float v[DD];
        v[0] = traffic[i];
        v[1] = packets[i];
#pragma unroll
        for (int k = 0; k < 12; k++) v[2 + k] = tdp[i * 12 + k];
#pragma unroll
        for (int k = 14; k < DD; k++) v[k] = 0.0f;
#pragma unroll
        for (int k = 0; k < DD; k++) path_state[i * DD + k] = v[k];
        lens[i] = 0;
    }
    if (i < NL) {
        link_state[i * DD] = capacity[i];
#pragma unroll
        for (int k = 1; k < DD; k++) link_state[i * DD + k] = 0.0f;
    }
}

__global__ __launch_bounds__(256) void k_lens(const int* __restrict__ path_ids,
                                              const int* __restrict__ seq_path,
                                              int* __restrict__ lens) {
    int e = blockIdx.x * 256 + threadIdx.x;
    if (e < NE) atomicMax(&lens[path_ids[e]], seq_path[e] + 1);
}

__global__ __launch_bounds__(256) void k_gru_paths(
    const float* __restrict__ link_state, float* __restrict__ path_state,
    const int* __restrict__ link_to_path, const int* __restrict__ lens,
    const float* __restrict__ Wi, const float* __restrict__ Wh,
    const float* __restrict__ bi, const float* __restrict__ bh) {
    __shared__ float sWi[NG * DD], sWh[NG * DD], sbi[NG], sbh[NG];
    for (int i = threadIdx.x; i < NG * DD; i += 256) {
        sWi[i] = Wi[i];
        sWh[i] = Wh[i];
    }
    if (threadIdx.x < NG) {
        sbi[threadIdx.x] = bi[threadIdx.x];
        sbh[threadIdx.x] = bh[threadIdx.x];
    }
    __syncthreads();
    int p = blockIdx.x * 256 + threadIdx.x;
    if (p >= NP) return;
    float h[DD];
#pragma unroll
    for (int k = 0; k < DD; k++) h[k] = path_state[p * DD + k];
    int len = lens[p];
    for (int s = 0; s < PLEN; s++) {
        if (s >= len) break;
        int li = link_to_path[p * PLEN + s];
        float x[DD];
#pragma unroll
        for (int k = 0; k < DD; k++) x[k] = link_state[li * DD + k];
        gru_step(sWi, sWh, sbi, sbh, x, h);
    }
#pragma unroll
    for (int k = 0; k < DD; k++) path_state[p * DD + k] = h[k];
}

__global__ __launch_bounds__(256) void k_zero(float* __restrict__ p, int n) {
    int i = blockIdx.x * 256 + threadIdx.x;
    if (i < n) p[i] = 0.0f;
}

__global__ __launch_bounds__(256) void k_scatter(
    const float* __restrict__ path_state, const int* __restrict__ path_to_link,
    const int* __restrict__ seq_links, float* __restrict__ path_sum) {
    int idx = blockIdx.x * 256 + threadIdx.x;
    if (idx >= NE * DD) return;
    int e = idx >> 5;
    int d = idx & 31;
    int p = path_to_link[e];
    int l = seq_links[e];
    atomicAdd(&path_sum[l * DD + d], path_state[p * DD + d]);
}

__global__ __launch_bounds__(256) void k_gru_links(
    const float* __restrict__ x_all, float* __restrict__ h_all,
    const float* __restrict__ Wi, const float* __restrict__ Wh,
    const float* __restrict__ bi, const float* __restrict__ bh) {
    __shared__ float sWi[NG * DD], sWh[NG * DD], sbi[NG], sbh[NG];
    for (int i = threadIdx.x; i < NG * DD; i += 256) {
        sWi[i] = Wi[i];
        sWh[i] = Wh[i];
    }
    if (threadIdx.x < NG) {
        sbi[threadIdx.x] = bi[threadIdx.x];
        sbh[threadIdx.x] = bh[threadIdx.x];
    }
    __syncthreads();
    int i = blockIdx.x * 256 + threadIdx.x;
    if (i >= NL) return;
    float x[DD], h[DD];
#pragma unroll
    for (int k = 0; k < DD; k++) {
        x[k] = x_all[i * DD + k];
        h[k] = h_all[i * DD + k];
    }
    gru_step(sWi, sWh, sbi, sbh, x, h);
#pragma unroll
    for (int k = 0; k < DD; k++) h_all[i * DD + k] = h[k];
}

// Fused readout: 64 paths per block.
//   phase1: r1 = relu(ps @ W1.T + b1) into LDS (row stride 257 -> 2-way, free)
//   phase2: W2 staged in 64-row LDS chunks; each thread owns (path pi, 16 j's
//           per chunk) with register-cached r1 sub-rows; accumulate W3-dot.
__global__ __launch_bounds__(256) void k_readout(
    const float* __restrict__ path_state, float* __restrict__ out,
    const float* __restrict__ W1, const float* __restrict__ b1,
    const float* __restrict__ W2, const float* __restrict__ b2,
    const float* __restrict__ W3, const float* __restrict__ b3) {
    __shared__ float smem[64 * 257 + 64 * 256 + 256];  // 132352 B
    float* sr1  = smem;               // [64][257]
    float* sbuf = smem + 64 * 257;    // W1t (32KB) then W2 chunks (64KB)
    float* sred = sbuf + 64 * 256;    // [256]
    int tid = threadIdx.x;
    int p0 = blockIdx.x * 64;

    // stage W1 transposed: sbuf[k*256 + j] = W1[j*32 + k]
    for (int idx = tid; idx < RUU * DD; idx += 256) {
        int j = idx >> 5, k = idx & 31;
        sbuf[k * RUU + j] = W1[idx];
    }
    __syncthreads();

    // phase 1: r1 for 64 paths; loop m over paths, thread tid computes col tid
    float bb1 = b1[tid];
    for (int m = 0; m < 64; m++) {
        int p = p0 + m;
        int pc = (p < NP) ? p : (NP - 1);
        float acc = bb1;
#pragma unroll 8
        for (int k = 0; k < DD; k++)
            acc = fmaf(path_state[pc * DD + k], sbuf[k * RUU + tid], acc);
        sr1[m * 257 + tid] = fmaxf(acc, 0.0f);
    }

    // phase 2
    int pi = tid & 63;
    int jg = tid >> 6;
    float oacc = 0.0f;
    for (int c = 0; c < 4; c++) {
        __syncthreads();  // previous users of sbuf done
        for (int idx = tid; idx < 64 * RUU; idx += 256)
            sbuf[idx] = W2[c * 64 * RUU + idx];
        __syncthreads();
        float accs[16];
#pragma unroll
        for (int jl = 0; jl < 16; jl++) accs[jl] = b2[c * 64 + jg * 16 + jl];
        for (int kc = 0; kc < 8; kc++) {
            float rk[32];
#pragma unroll
            for (int kk = 0; kk < 32; kk++) rk[kk] = sr1[pi * 257 + kc * 32 + kk];
#pragma unroll
            for (int jl = 0; jl < 16; jl++) {
                float a = accs[jl];
                const float* wrow = &sbuf[(jg * 16 + jl) * RUU + kc * 32];
#pragma unroll
                for (int kk = 0; kk < 32; kk++) a = fmaf(rk[kk], wrow[kk], a);
                accs[jl] = a;
            }
        }
#pragma unroll
        for (int jl = 0; jl < 16; jl++)
            oacc = fmaf(W3[c * 64 + jg * 16 + jl], fmaxf(accs[jl], 0.0f), oacc);
    }
    sred[tid] = oacc;
    __syncthreads();
    if (tid < 64) {
        float v = sred[tid] + sred[tid + 64] + sred[tid + 128] + sred[tid + 192] + b3[0];
        int p = p0 + tid;
        if (p < NP) out[p] = v;
    }
}

extern "C" void kernel_launch(void* const* d_in, const int* in_sizes, int n_in,
                              void* d_out, int out_size, void* d_ws, size_t ws_size,
                              hipStream_t stream) {
    const float* traffic  = (const float*)d_in[0];
    const float* packets  = (const float*)d_in[1];
    const float* tdp      = (const float*)d_in[2];
    const float* capacity = (const float*)d_in[3];
    const int* link_to_path = (const int*)d_in[4];
    const int* path_ids     = (const int*)d_in[5];
    const int* seq_path     = (const int*)d_in[6];
    const int* path_to_link = (const int*)d_in[7];
    const int* seq_links    = (const int*)d_in[8];
    const float* Wi_p = (const float*)d_in[11];
    const float* Wh_p = (const float*)d_in[12];
    const float* bi_p = (const float*)d_in[13];
    const float* bh_p = (const float*)d_in[14];
    const float* Wi_l = (const float*)d_in[15];
    const float* Wh_l = (const float*)d_in[16];
    const float* bi_l = (const float*)d_in[17];
    const float* bh_l = (const float*)d_in[18];
    const float* W1 = (const float*)d_in[19];
    const float* b1 = (const float*)d_in[20];
    const float* W2 = (const float*)d_in[21];
    const float* b2 = (const float*)d_in[22];
    const float* W3 = (const float*)d_in[23];
    const float* b3 = (const float*)d_in[24];
    float* out = (float*)d_out;

    float* path_state = (float*)d_ws;                // NP*32 f32 = 6.4 MB
    float* link_state = path_state + (size_t)NP * DD;  // NL*32
    float* path_sum   = link_state + (size_t)NL * DD;  // NL*32
    int*   lens       = (int*)(path_sum + (size_t)NL * DD);  // NP ints

    k_init<<<(NP + 255) / 256, 256, 0, stream>>>(traffic, packets, tdp, capacity,
                                                 path_state, link_state, lens);
    k_lens<<<(NE + 255) / 256, 256, 0, stream>>>(path_ids, seq_path, lens);
    for (int t = 0; t < TITERS; t++) {
        k_gru_paths<<<(NP + 255) / 256, 256, 0, stream>>>(
            link_state, path_state, link_to_path, lens, Wi_p, Wh_p, bi_p, bh_p);
        k_zero<<<(NL * DD + 255) / 256, 256, 0, stream>>>(path_sum, NL * DD);
        k_scatter<<<(NE * DD + 255) / 256, 256, 0, stream>>>(
            path_state, path_to_link, seq_links, path_sum);
        k_gru_links<<<(NL + 255) / 256, 256, 0, stream>>>(
            path_sum, link_state, Wi_l, Wh_l, bi_l, bh_l);
    }
    k_readout<<<(NP + 63) / 64, 256, 0, stream>>>(path_state, out, W1, b1, W2,
                                                  b2, W3, b3);
}

// Round 2
// 2604.155 us; speedup vs baseline: 11.1358x; 11.1358x over previous
//
#include <hip/hip_runtime.h>

#define NP 50000
#define NL 10000
#define PLEN 5
#define NE (NP * PLEN)
#define DD 32
#define NG 96   /* 3*32 */
#define RUU 256
#define TITERS 8

__device__ __forceinline__ float sigmoidf_(float a) {
    return 1.0f / (1.0f + __expf(-a));
}
__device__ __forceinline__ float tanhf_(float a) {
    a = fminf(fmaxf(a, -15.0f), 15.0f);
    float t = __expf(2.0f * a);
    return (t - 1.0f) / (t + 1.0f);
}

// GRU step, gate loop in pairs (bounded register pressure), float4 LDS
// broadcast reads for weights.
__device__ __forceinline__ void gru_step(const float4* __restrict__ sWi4,
                                         const float4* __restrict__ sWh4,
                                         const float* __restrict__ sbi,
                                         const float* __restrict__ sbh,
                                         const float* __restrict__ x,
                                         float* __restrict__ h) {
    float hn[DD];
#pragma unroll 2
    for (int j = 0; j < DD; j++) {
        float ir  = sbi[j];
        float iz  = sbi[j + 32];
        float inn = sbi[j + 64];
        float hr  = sbh[j];
        float hz  = sbh[j + 32];
        float hnn = sbh[j + 64];
#pragma unroll
        for (int kc = 0; kc < 8; kc++) {
            float4 wa = sWi4[j * 8 + kc];
            float4 wb = sWi4[(j + 32) * 8 + kc];
            float4 wc = sWi4[(j + 64) * 8 + kc];
            float4 wd = sWh4[j * 8 + kc];
            float4 we = sWh4[(j + 32) * 8 + kc];
            float4 wf = sWh4[(j + 64) * 8 + kc];
            float x0 = x[kc * 4], x1 = x[kc * 4 + 1], x2 = x[kc * 4 + 2], x3 = x[kc * 4 + 3];
            float h0 = h[kc * 4], h1 = h[kc * 4 + 1], h2 = h[kc * 4 + 2], h3 = h[kc * 4 + 3];
            ir  = fmaf(x0, wa.x, fmaf(x1, wa.y, fmaf(x2, wa.z, fmaf(x3, wa.w, ir))));
            iz  = fmaf(x0, wb.x, fmaf(x1, wb.y, fmaf(x2, wb.z, fmaf(x3, wb.w, iz))));
            inn = fmaf(x0, wc.x, fmaf(x1, wc.y, fmaf(x2, wc.z, fmaf(x3, wc.w, inn))));
            hr  = fmaf(h0, wd.x, fmaf(h1, wd.y, fmaf(h2, wd.z, fmaf(h3, wd.w, hr))));
            hz  = fmaf(h0, we.x, fmaf(h1, we.y, fmaf(h2, we.z, fmaf(h3, we.w, hz))));
            hnn = fmaf(h0, wf.x, fmaf(h1, wf.y, fmaf(h2, wf.z, fmaf(h3, wf.w, hnn))));
        }
        float r = sigmoidf_(ir + hr);
        float z = sigmoidf_(iz + hz);
        float n = tanhf_(inn + r * hnn);
        hn[j] = (1.0f - z) * n + z * h[j];
    }
#pragma unroll
    for (int j = 0; j < DD; j++) h[j] = hn[j];
}

__global__ __launch_bounds__(256) void k_init(
    const float* __restrict__ traffic, const float* __restrict__ packets,
    const float* __restrict__ tdp, const float* __restrict__ capacity,
    float* __restrict__ path_state, float* __restrict__ link_state,
    int* __restrict__ lens) {
    int i = blockIdx.x * 256 + threadIdx.x;
    if (i < NP) {
        float v[DD];
        v[0] = traffic[i];
        v[1] = packets[i];
#pragma unroll
        for (int k = 0; k < 12; k++) v[2 + k] = tdp[i * 12 + k];
#pragma unroll
        for (int k = 14; k < DD; k++) v[k] = 0.0f;
#pragma unroll
        for (int k = 0; k < DD; k++) path_state[i * DD + k] = v[k];
        lens[i] = 0;
    }
    if (i < NL) {
        link_state[i * DD] = capacity[i];
#pragma unroll
        for (int k = 1; k < DD; k++) link_state[i * DD + k] = 0.0f;
    }
}

__global__ __launch_bounds__(256) void k_lens(const int* __restrict__ path_ids,
                                              const int* __restrict__ seq_path,
                                              int* __restrict__ lens) {
    int e = blockIdx.x * 256 + threadIdx.x;
    if (e < NE) atomicMax(&lens[path_ids[e]], seq_path[e] + 1);
}

__global__ __launch_bounds__(256) void k_gru_paths(
    const float* __restrict__ link_state, float* __restrict__ path_state,
    const int* __restrict__ link_to_path, const int* __restrict__ lens,
    const float* __restrict__ Wi, const float* __restrict__ Wh,
    const float* __restrict__ bi, const float* __restrict__ bh) {
    __shared__ float4 sWi4[NG * 8], sWh4[NG * 8];
    __shared__ float sbi[NG], sbh[NG];
    const float4* Wi4 = (const float4*)Wi;
    const float4* Wh4 = (const float4*)Wh;
    for (int i = threadIdx.x; i < NG * 8; i += 256) {
        sWi4[i] = Wi4[i];
        sWh4[i] = Wh4[i];
    }
    if (threadIdx.x < NG) {
        sbi[threadIdx.x] = bi[threadIdx.x];
        sbh[threadIdx.x] = bh[threadIdx.x];
    }
    __syncthreads();
    int p = blockIdx.x * 256 + threadIdx.x;
    if (p >= NP) return;
    float h[DD];
#pragma unroll
    for (int kc = 0; kc < 8; kc++)
        *(float4*)&h[kc * 4] = *(const float4*)&path_state[p * DD + kc * 4];
    int len = lens[p];
    for (int s = 0; s < PLEN; s++) {
        if (s >= len) break;
        int li = link_to_path[p * PLEN + s];
        float x[DD];
#pragma unroll
        for (int kc = 0; kc < 8; kc++)
            *(float4*)&x[kc * 4] = *(const float4*)&link_state[li * DD + kc * 4];
        gru_step(sWi4, sWh4, sbi, sbh, x, h);
    }
#pragma unroll
    for (int kc = 0; kc < 8; kc++)
        *(float4*)&path_state[p * DD + kc * 4] = *(const float4*)&h[kc * 4];
}

__global__ __launch_bounds__(256) void k_zero(float* __restrict__ p, int n) {
    int i = blockIdx.x * 256 + threadIdx.x;
    if (i < n) p[i] = 0.0f;
}

__global__ __launch_bounds__(256) void k_scatter(
    const float* __restrict__ path_state, const int* __restrict__ path_to_link,
    const int* __restrict__ seq_links, float* __restrict__ path_sum) {
    int idx = blockIdx.x * 256 + threadIdx.x;
    if (idx >= NE * DD) return;
    int e = idx >> 5;
    int d = idx & 31;
    int p = path_to_link[e];
    int l = seq_links[e];
    atomicAdd(&path_sum[l * DD + d], path_state[p * DD + d]);
}

__global__ __launch_bounds__(256) void k_gru_links(
    const float* __restrict__ x_all, float* __restrict__ h_all,
    const float* __restrict__ Wi, const float* __restrict__ Wh,
    const float* __restrict__ bi, const float* __restrict__ bh) {
    __shared__ float4 sWi4[NG * 8], sWh4[NG * 8];
    __shared__ float sbi[NG], sbh[NG];
    const float4* Wi4 = (const float4*)Wi;
    const float4* Wh4 = (const float4*)Wh;
    for (int i = threadIdx.x; i < NG * 8; i += 256) {
        sWi4[i] = Wi4[i];
        sWh4[i] = Wh4[i];
    }
    if (threadIdx.x < NG) {
        sbi[threadIdx.x] = bi[threadIdx.x];
        sbh[threadIdx.x] = bh[threadIdx.x];
    }
    __syncthreads();
    int i = blockIdx.x * 256 + threadIdx.x;
    if (i >= NL) return;
    float x[DD], h[DD];
#pragma unroll
    for (int kc = 0; kc < 8; kc++) {
        *(float4*)&x[kc * 4] = *(const float4*)&x_all[i * DD + kc * 4];
        *(float4*)&h[kc * 4] = *(const float4*)&h_all[i * DD + kc * 4];
    }
    gru_step(sWi4, sWh4, sbi, sbh, x, h);
#pragma unroll
    for (int kc = 0; kc < 8; kc++)
        *(float4*)&h_all[i * DD + kc * 4] = *(const float4*)&h[kc * 4];
}

// Fused readout: 64 paths per block.
__global__ __launch_bounds__(256) void k_readout(
    const float* __restrict__ path_state, float* __restrict__ out,
    const float* __restrict__ W1, const float* __restrict__ b1,
    const float* __restrict__ W2, const float* __restrict__ b2,
    const float* __restrict__ W3, const float* __restrict__ b3) {
    __shared__ float smem[64 * 257 + 64 * 256 + 256];  // 132352 B
    float* sr1  = smem;               // [64][257]
    float* sbuf = smem + 64 * 257;    // W1t (32KB) then W2 chunks (64KB)
    float* sred = sbuf + 64 * 256;    // [256]
    int tid = threadIdx.x;
    int p0 = blockIdx.x * 64;

    // stage W1 transposed: sbuf[k*256 + j] = W1[j*32 + k]
    for (int idx = tid; idx < RUU * DD; idx += 256) {
        int j = idx >> 5, k = idx & 31;
        sbuf[k * RUU + j] = W1[idx];
    }
    __syncthreads();

    float bb1 = b1[tid];
    for (int m = 0; m < 64; m++) {
        int p = p0 + m;
        int pc = (p < NP) ? p : (NP - 1);
        float acc = bb1;
#pragma unroll 8
        for (int k = 0; k < DD; k++)
            acc = fmaf(path_state[pc * DD + k], sbuf[k * RUU + tid], acc);
        sr1[m * 257 + tid] = fmaxf(acc, 0.0f);
    }

    int pi = tid & 63;
    int jg = tid >> 6;
    float oacc = 0.0f;
    for (int c = 0; c < 4; c++) {
        __syncthreads();
        for (int idx = tid; idx < 64 * RUU; idx += 256)
            sbuf[idx] = W2[c * 64 * RUU + idx];
        __syncthreads();
        float accs[16];
#pragma unroll
        for (int jl = 0; jl < 16; jl++) accs[jl] = b2[c * 64 + jg * 16 + jl];
        for (int kc = 0; kc < 8; kc++) {
            float rk[32];
#pragma unroll
            for (int kk = 0; kk < 32; kk++) rk[kk] = sr1[pi * 257 + kc * 32 + kk];
#pragma unroll
            for (int jl = 0; jl < 16; jl++) {
                float a = accs[jl];
                const float* wrow = &sbuf[(jg * 16 + jl) * RUU + kc * 32];
#pragma unroll
                for (int kk = 0; kk < 32; kk++) a = fmaf(rk[kk], wrow[kk], a);
                accs[jl] = a;
            }
        }
#pragma unroll
        for (int jl = 0; jl < 16; jl++)
            oacc = fmaf(W3[c * 64 + jg * 16 + jl], fmaxf(accs[jl], 0.0f), oacc);
    }
    sred[tid] = oacc;
    __syncthreads();
    if (tid < 64) {
        float v = sred[tid] + sred[tid + 64] + sred[tid + 128] + sred[tid + 192] + b3[0];
        int p = p0 + tid;
        if (p < NP) out[p] = v;
    }
}

extern "C" void kernel_launch(void* const* d_in, const int* in_sizes, int n_in,
                              void* d_out, int out_size, void* d_ws, size_t ws_size,
                              hipStream_t stream) {
    const float* traffic  = (const float*)d_in[0];
    const float* packets  = (const float*)d_in[1];
    const float* tdp      = (const float*)d_in[2];
    const float* capacity = (const float*)d_in[3];
    const int* link_to_path = (const int*)d_in[4];
    const int* path_ids     = (const int*)d_in[5];
    const int* seq_path     = (const int*)d_in[6];
    const int* path_to_link = (const int*)d_in[7];
    const int* seq_links    = (const int*)d_in[8];
    const float* Wi_p = (const float*)d_in[11];
    const float* Wh_p = (const float*)d_in[12];
    const float* bi_p = (const float*)d_in[13];
    const float* bh_p = (const float*)d_in[14];
    const float* Wi_l = (const float*)d_in[15];
    const float* Wh_l = (const float*)d_in[16];
    const float* bi_l = (const float*)d_in[17];
    const float* bh_l = (const float*)d_in[18];
    const float* W1 = (const float*)d_in[19];
    const float* b1 = (const float*)d_in[20];
    const float* W2 = (const float*)d_in[21];
    const float* b2 = (const float*)d_in[22];
    const float* W3 = (const float*)d_in[23];
    const float* b3 = (const float*)d_in[24];
    float* out = (float*)d_out;

    float* path_state = (float*)d_ws;                // NP*32 f32 = 6.4 MB
    float* link_state = path_state + (size_t)NP * DD;  // NL*32
    float* path_sum   = link_state + (size_t)NL * DD;  // NL*32
    int*   lens       = (int*)(path_sum + (size_t)NL * DD);  // NP ints

    k_init<<<(NP + 255) / 256, 256, 0, stream>>>(traffic, packets, tdp, capacity,
                                                 path_state, link_state, lens);
    k_lens<<<(NE + 255) / 256, 256, 0, stream>>>(path_ids, seq_path, lens);
    for (int t = 0; t < TITERS; t++) {
        k_gru_paths<<<(NP + 255) / 256, 256, 0, stream>>>(
            link_state, path_state, link_to_path, lens, Wi_p, Wh_p, bi_p, bh_p);
        k_zero<<<(NL * DD + 255) / 256, 256, 0, stream>>>(path_sum, NL * DD);
        k_scatter<<<(NE * DD + 255) / 256, 256, 0, stream>>>(
            path_state, path_to_link, seq_links, path_sum);
        k_gru_links<<<(NL + 255) / 256, 256, 0, stream>>>(
            path_sum, link_state, Wi_l, Wh_l, bi_l, bh_l);
    }
    k_readout<<<(NP + 63) / 64, 256, 0, stream>>>(path_state, out, W1, b1, W2,
                                                  b2, W3, b3);
}

// Round 3
// 2593.454 us; speedup vs baseline: 11.1818x; 1.0041x over previous
//
#include <hip/hip_runtime.h>

#define NP 50000
#define NL 10000
#define PLEN 5
#define NE (NP * PLEN)
#define DD 32
#define NG 96   /* 3*32 */
#define RUU 256
#define TITERS 8

__device__ __forceinline__ float sigmoidf_(float a) {
    return 1.0f / (1.0f + __expf(-a));
}
__device__ __forceinline__ float tanhf_(float a) {
    a = fminf(fmaxf(a, -15.0f), 15.0f);
    float t = __expf(2.0f * a);
    return (t - 1.0f) / (t + 1.0f);
}

// Partial GRU gate evaluation: compute hnew[jbase..jbase+NJ) only.
// Weights via float4 LDS broadcast. x,h full 32 in registers.
template <int NJ>
__device__ __forceinline__ void gru_gates(const float4* __restrict__ sWi4,
                                          const float4* __restrict__ sWh4,
                                          const float* __restrict__ sbi,
                                          const float* __restrict__ sbh,
                                          const float* __restrict__ x,
                                          const float* __restrict__ h,
                                          int jbase, float* __restrict__ hn) {
#pragma unroll 2
    for (int jj = 0; jj < NJ; jj++) {
        int j = jbase + jj;
        float ir  = sbi[j];
        float iz  = sbi[j + 32];
        float inn = sbi[j + 64];
        float hr  = sbh[j];
        float hz  = sbh[j + 32];
        float hnn = sbh[j + 64];
#pragma unroll
        for (int kc = 0; kc < 8; kc++) {
            float4 wa = sWi4[j * 8 + kc];
            float4 wb = sWi4[(j + 32) * 8 + kc];
            float4 wc = sWi4[(j + 64) * 8 + kc];
            float4 wd = sWh4[j * 8 + kc];
            float4 we = sWh4[(j + 32) * 8 + kc];
            float4 wf = sWh4[(j + 64) * 8 + kc];
            float x0 = x[kc * 4], x1 = x[kc * 4 + 1], x2 = x[kc * 4 + 2], x3 = x[kc * 4 + 3];
            float h0 = h[kc * 4], h1 = h[kc * 4 + 1], h2 = h[kc * 4 + 2], h3 = h[kc * 4 + 3];
            ir  = fmaf(x0, wa.x, fmaf(x1, wa.y, fmaf(x2, wa.z, fmaf(x3, wa.w, ir))));
            iz  = fmaf(x0, wb.x, fmaf(x1, wb.y, fmaf(x2, wb.z, fmaf(x3, wb.w, iz))));
            inn = fmaf(x0, wc.x, fmaf(x1, wc.y, fmaf(x2, wc.z, fmaf(x3, wc.w, inn))));
            hr  = fmaf(h0, wd.x, fmaf(h1, wd.y, fmaf(h2, wd.z, fmaf(h3, wd.w, hr))));
            hz  = fmaf(h0, we.x, fmaf(h1, we.y, fmaf(h2, we.z, fmaf(h3, we.w, hz))));
            hnn = fmaf(h0, wf.x, fmaf(h1, wf.y, fmaf(h2, wf.z, fmaf(h3, wf.w, hnn))));
        }
        float r = sigmoidf_(ir + hr);
        float z = sigmoidf_(iz + hz);
        float n = tanhf_(inn + r * hnn);
        hn[jj] = (1.0f - z) * n + z * h[j];
    }
}

__device__ __forceinline__ void stage_weights(const float* __restrict__ Wi,
                                              const float* __restrict__ Wh,
                                              const float* __restrict__ bi,
                                              const float* __restrict__ bh,
                                              float4* sWi4, float4* sWh4,
                                              float* sbi, float* sbh) {
    const float4* Wi4 = (const float4*)Wi;
    const float4* Wh4 = (const float4*)Wh;
    for (int i = threadIdx.x; i < NG * 8; i += 256) {
        sWi4[i] = Wi4[i];
        sWh4[i] = Wh4[i];
    }
    if (threadIdx.x < NG) {
        sbi[threadIdx.x] = bi[threadIdx.x];
        sbh[threadIdx.x] = bh[threadIdx.x];
    }
}

__global__ __launch_bounds__(256) void k_init(
    const float* __restrict__ traffic, const float* __restrict__ packets,
    const float* __restrict__ tdp, const float* __restrict__ capacity,
    float* __restrict__ path_state, float* __restrict__ link_state,
    float* __restrict__ path_sum, int* __restrict__ lens) {
    int i = blockIdx.x * 256 + threadIdx.x;
    if (i < NP) {
        float v[DD];
        v[0] = traffic[i];
        v[1] = packets[i];
#pragma unroll
        for (int k = 0; k < 12; k++) v[2 + k] = tdp[i * 12 + k];
#pragma unroll
        for (int k = 14; k < DD; k++) v[k] = 0.0f;
#pragma unroll
        for (int k = 0; k < DD; k++) path_state[i * DD + k] = v[k];
        lens[i] = 0;
    }
    if (i < NL) {
        link_state[i * DD] = capacity[i];
#pragma unroll
        for (int k = 1; k < DD; k++) link_state[i * DD + k] = 0.0f;
#pragma unroll
        for (int k = 0; k < DD; k++) path_sum[i * DD + k] = 0.0f;
    }
}

__global__ __launch_bounds__(256) void k_lens(const int* __restrict__ path_ids,
                                              const int* __restrict__ seq_path,
                                              int* __restrict__ lens) {
    int e = blockIdx.x * 256 + threadIdx.x;
    if (e < NE) atomicMax(&lens[path_ids[e]], seq_path[e] + 1);
}

// 4-way j-split path GRU: lanes (q*16+s) q=0..3 handle path (base + s),
// each computing 8 of 32 h-outputs; full h rebuilt per step via shfl_xor.
__global__ __launch_bounds__(256) void k_gru_paths(
    const float* __restrict__ link_state, float* __restrict__ path_state,
    const int* __restrict__ link_to_path, const int* __restrict__ lens,
    const float* __restrict__ Wi, const float* __restrict__ Wh,
    const float* __restrict__ bi, const float* __restrict__ bh) {
    __shared__ float4 sWi4[NG * 8], sWh4[NG * 8];
    __shared__ float sbi[NG], sbh[NG];
    stage_weights(Wi, Wh, bi, bh, sWi4, sWh4, sbi, sbh);
    __syncthreads();

    int tid = threadIdx.x;
    int lane = tid & 63;
    int wave = tid >> 6;
    int s_ = lane & 15;   // path slot within wave
    int q = lane >> 4;    // quarter: j-range q*8..q*8+7
    int b = q >> 1;       // half: 0 -> j 0..15, 1 -> j 16..31
    int p = blockIdx.x * 64 + wave * 16 + s_;
    if (p >= NP) return;

    float h[DD];
#pragma unroll
    for (int kc = 0; kc < 8; kc++)
        *(float4*)&h[kc * 4] = *(const float4*)&path_state[p * DD + kc * 4];
    int len = lens[p];
    int jbase = q * 8;

    for (int st = 0; st < PLEN; st++) {
        if (st >= len) break;
        int li = link_to_path[p * PLEN + st];
        float x[DD];
#pragma unroll
        for (int kc = 0; kc < 8; kc++)
            *(float4*)&x[kc * 4] = *(const float4*)&link_state[li * DD + kc * 4];
        float hn[8];
        gru_gates<8>(sWi4, sWh4, sbi, sbh, x, h, jbase, hn);
        // rebuild full h: round 1 (xor 16) within half, round 2 (xor 32)
        float hq1[8];
#pragma unroll
        for (int jj = 0; jj < 8; jj++) hq1[jj] = __shfl_xor(hn[jj], 16);
        float h16[16];
        bool qodd = (q & 1) != 0;
#pragma unroll
        for (int jj = 0; jj < 8; jj++) {
            h16[jj]     = qodd ? hq1[jj] : hn[jj];
            h16[8 + jj] = qodd ? hn[jj] : hq1[jj];
        }
        float o16[16];
#pragma unroll
        for (int i = 0; i < 16; i++) o16[i] = __shfl_xor(h16[i], 32);
        bool bodd = (b != 0);
#pragma unroll
        for (int i = 0; i < 16; i++) {
            h[i]      = bodd ? o16[i] : h16[i];
            h[16 + i] = bodd ? h16[i] : o16[i];
        }
    }
    // each thread stores its own quarter
    *(float4*)&path_state[p * DD + jbase]     = *(const float4*)&h[jbase];
    *(float4*)&path_state[p * DD + jbase + 4] = *(const float4*)&h[jbase + 4];
}

// scatter: one thread per (edge, 4-dim group)
__global__ __launch_bounds__(256) void k_scatter(
    const float* __restrict__ path_state, const int* __restrict__ path_to_link,
    const int* __restrict__ seq_links, float* __restrict__ path_sum) {
    int idx = blockIdx.x * 256 + threadIdx.x;
    if (idx >= NE * 8) return;
    int e = idx >> 3;
    int d0 = (idx & 7) * 4;
    int p = path_to_link[e];
    int l = seq_links[e];
    float4 v = *(const float4*)&path_state[p * DD + d0];
    atomicAdd(&path_sum[l * DD + d0 + 0], v.x);
    atomicAdd(&path_sum[l * DD + d0 + 1], v.y);
    atomicAdd(&path_sum[l * DD + d0 + 2], v.z);
    atomicAdd(&path_sum[l * DD + d0 + 3], v.w);
}

// 8-way j-split link GRU (single step -> no exchange needed).
// Also zeroes path_sum for the next iteration.
__global__ __launch_bounds__(256) void k_gru_links(
    float* __restrict__ path_sum, float* __restrict__ link_state,
    const float* __restrict__ Wi, const float* __restrict__ Wh,
    const float* __restrict__ bi, const float* __restrict__ bh) {
    __shared__ float4 sWi4[NG * 8], sWh4[NG * 8];
    __shared__ float sbi[NG], sbh[NG];
    stage_weights(Wi, Wh, bi, bh, sWi4, sWh4, sbi, sbh);
    __syncthreads();

    int tid = threadIdx.x;
    int lane = tid & 63;
    int wave = tid >> 6;
    int s_ = lane & 7;
    int e8 = lane >> 3;   // eighth: j-range e8*4..e8*4+3
    int i = blockIdx.x * 32 + wave * 8 + s_;
    if (i >= NL) return;

    float x[DD], h[DD];
#pragma unroll
    for (int kc = 0; kc < 8; kc++) {
        *(float4*)&x[kc * 4] = *(const float4*)&path_sum[i * DD + kc * 4];
        *(float4*)&h[kc * 4] = *(const float4*)&link_state[i * DD + kc * 4];
    }
    float hn[4];
    gru_gates<4>(sWi4, sWh4, sbi, sbh, x, h, e8 * 4, hn);
    *(float4*)&link_state[i * DD + e8 * 4] = *(const float4*)&hn[0];
    // zero path_sum for next iteration's scatter
    float4 z4 = make_float4(0.f, 0.f, 0.f, 0.f);
    *(float4*)&path_sum[i * DD + e8 * 4] = z4;
}

// Readout: 64 paths/block, 256 threads. LDS = sr1[64][260] + 8KB buffer
// (path_state tile, then W2 8-row chunks) + 1KB reduce = 75.8KB -> 2 blk/CU.
#define SR1_STRIDE 260
__global__ __launch_bounds__(256) void k_readout(
    const float* __restrict__ path_state, float* __restrict__ out,
    const float* __restrict__ W1, const float* __restrict__ b1,
    const float* __restrict__ W2, const float* __restrict__ b2,
    const float* __restrict__ W3, const float* __restrict__ b3) {
    __shared__ float sr1[64 * SR1_STRIDE];   // 66560 B
    __shared__ float sbuf[8 * RUU];          // 8192 B: sps tile then W2 chunks
    __shared__ float sred[256];              // 1024 B
    int tid = threadIdx.x;
    int p0 = blockIdx.x * 64;

    // stage 64x32 path_state tile into sbuf (contiguous, coalesced)
    {
        const float4* src = (const float4*)&path_state[(size_t)p0 * DD];
        float4* dst = (float4*)sbuf;
#pragma unroll
        for (int r = 0; r < 2; r++) dst[tid + r * 256] = src[tid + r * 256];
    }
    // W1 row of column tid into registers
    float w1r[DD];
#pragma unroll
    for (int kc = 0; kc < 8; kc++)
        *(float4*)&w1r[kc * 4] = *(const float4*)&W1[tid * DD + kc * 4];
    float bb1 = b1[tid];
    __syncthreads();

    // phase 1: r1[m][tid] for all 64 paths (sps broadcast reads)
    for (int m = 0; m < 64; m++) {
        float acc = bb1;
        const float4* xr = (const float4*)&sbuf[m * DD];
#pragma unroll
        for (int kc = 0; kc < 8; kc++) {
            float4 xv = xr[kc];
            acc = fmaf(xv.x, w1r[kc * 4 + 0],
                  fmaf(xv.y, w1r[kc * 4 + 1],
                  fmaf(xv.z, w1r[kc * 4 + 2],
                  fmaf(xv.w, w1r[kc * 4 + 3], acc))));
        }
        sr1[m * SR1_STRIDE + tid] = fmaxf(acc, 0.0f);
    }

    // phase 2: 32 chunks of 8 W2 rows; wave jg handles rows jg*2, jg*2+1
    int pi = tid & 63;
    int jg = tid >> 6;
    float oacc = 0.0f;
    for (int c = 0; c < 32; c++) {
        __syncthreads();
        {
            const float4* src = (const float4*)&W2[c * 8 * RUU];
            float4* dst = (float4*)sbuf;
#pragma unroll
            for (int r = 0; r < 2; r++) dst[tid + r * 256] = src[tid + r * 256];
        }
        __syncthreads();
        int j0 = c * 8 + jg * 2;
        float a0 = b2[j0], a1 = b2[j0 + 1];
#pragma unroll
        for (int kc = 0; kc < 8; kc++) {
            float rk[32];
            const float4* rs = (const float4*)&sr1[pi * SR1_STRIDE + kc * 32];
#pragma unroll
            for (int t4 = 0; t4 < 8; t4++) *(float4*)&rk[t4 * 4] = rs[t4];
            const float4* w0 = (const float4*)&sbuf[(jg * 2) * RUU + kc * 32];
            const float4* w1_ = (const float4*)&sbuf[(jg * 2 + 1) * RUU + kc * 32];
#pragma unroll
            for (int t4 = 0; t4 < 8; t4++) {
                float4 wv0 = w0[t4];
                float4 wv1 = w1_[t4];
                a0 = fmaf(rk[t4 * 4 + 0], wv0.x, fmaf(rk[t4 * 4 + 1], wv0.y,
                     fmaf(rk[t4 * 4 + 2], wv0.z, fmaf(rk[t4 * 4 + 3], wv0.w, a0))));
                a1 = fmaf(rk[t4 * 4 + 0], wv1.x, fmaf(rk[t4 * 4 + 1], wv1.y,
                     fmaf(rk[t4 * 4 + 2], wv1.z, fmaf(rk[t4 * 4 + 3], wv1.w, a1))));
            }
        }
        oacc = fmaf(W3[j0], fmaxf(a0, 0.0f), oacc);
        oacc = fmaf(W3[j0 + 1], fmaxf(a1, 0.0f), oacc);
    }
    sred[tid] = oacc;
    __syncthreads();
    if (tid < 64) {
        float v = sred[tid] + sred[tid + 64] + sred[tid + 128] + sred[tid + 192] + b3[0];
        int p = p0 + tid;
        if (p < NP) out[p] = v;
    }
}

extern "C" void kernel_launch(void* const* d_in, const int* in_sizes, int n_in,
                              void* d_out, int out_size, void* d_ws, size_t ws_size,
                              hipStream_t stream) {
    const float* traffic  = (const float*)d_in[0];
    const float* packets  = (const float*)d_in[1];
    const float* tdp      = (const float*)d_in[2];
    const float* capacity = (const float*)d_in[3];
    const int* link_to_path = (const int*)d_in[4];
    const int* path_ids     = (const int*)d_in[5];
    const int* seq_path     = (const int*)d_in[6];
    const int* path_to_link = (const int*)d_in[7];
    const int* seq_links    = (const int*)d_in[8];
    const float* Wi_p = (const float*)d_in[11];
    const float* Wh_p = (const float*)d_in[12];
    const float* bi_p = (const float*)d_in[13];
    const float* bh_p = (const float*)d_in[14];
    const float* Wi_l = (const float*)d_in[15];
    const float* Wh_l = (const float*)d_in[16];
    const float* bi_l = (const float*)d_in[17];
    const float* bh_l = (const float*)d_in[18];
    const float* W1 = (const float*)d_in[19];
    const float* b1 = (const float*)d_in[20];
    const float* W2 = (const float*)d_in[21];
    const float* b2 = (const float*)d_in[22];
    const float* W3 = (const float*)d_in[23];
    const float* b3 = (const float*)d_in[24];
    float* out = (float*)d_out;

    float* path_state = (float*)d_ws;                  // NP*32 f32
    float* link_state = path_state + (size_t)NP * DD;  // NL*32
    float* path_sum   = link_state + (size_t)NL * DD;  // NL*32
    int*   lens       = (int*)(path_sum + (size_t)NL * DD);  // NP ints

    k_init<<<(NP + 255) / 256, 256, 0, stream>>>(traffic, packets, tdp, capacity,
                                                 path_state, link_state, path_sum, lens);
    k_lens<<<(NE + 255) / 256, 256, 0, stream>>>(path_ids, seq_path, lens);
    for (int t = 0; t < TITERS; t++) {
        k_gru_paths<<<(NP * 4 + 255) / 256, 256, 0, stream>>>(
            link_state, path_state, link_to_path, lens, Wi_p, Wh_p, bi_p, bh_p);
        k_scatter<<<(NE * 8 + 255) / 256, 256, 0, stream>>>(
            path_state, path_to_link, seq_links, path_sum);
        k_gru_links<<<(NL * 8 + 255) / 256, 256, 0, stream>>>(
            path_sum, link_state, Wi_l, Wh_l, bi_l, bh_l);
    }
    k_readout<<<(NP + 63) / 64, 256, 0, stream>>>(path_state, out, W1, b1, W2,
                                                  b2, W3, b3);
}